// Round 1
// baseline (188.199 us; speedup 1.0000x reference)
//
#include <hip/hip_runtime.h>
#include <math.h>

#define GAMMA 0.5f

constexpr int B_ = 16;
constexpr int N_ = 2048;
constexpr int M_ = 2048;
constexpr int S_ = 2049;                      // N+1 == M+1
constexpr long long PLANE = (long long)S_ * S_;

// ---------------------------------------------------------------------------
// Kernel 1: gather pos0[b,i] = scores[b,i,gt0] and pos1[b,j] = scores[b,gt1,j]
// ---------------------------------------------------------------------------
__global__ void gather_pos(const float* __restrict__ scores,
                           const int* __restrict__ gt0,
                           const int* __restrict__ gt1,
                           float* __restrict__ pos0,
                           float* __restrict__ pos1) {
  int idx = blockIdx.x * blockDim.x + threadIdx.x;
  const int total = B_ * N_;
  if (idx < total) {
    int b = idx >> 11;            // / 2048
    int i = idx & (N_ - 1);
    int g = gt0[idx];
    if (g == -1) g = M_;
    pos0[idx] = scores[(long long)b * PLANE + (long long)i * S_ + g];
  } else if (idx < 2 * total) {
    int k = idx - total;
    int b = k >> 11;
    int j = k & (M_ - 1);
    int g = gt1[k];
    if (g == -1) g = N_;
    pos1[k] = scores[(long long)b * PLANE + (long long)g * S_ + j];
  }
}

// ---------------------------------------------------------------------------
// Kernel 2: one sweep over scores. Tile = 256 cols x 128 rows, 256 threads.
//   wave w handles rows i0 + w + 4k ; lane handles cols j0 + lane + 64q.
//   row-gap sums -> wave shuffle reduce -> float atomicAdd
//   col-gap sums -> LDS cross-wave reduce -> float atomicAdd
//   margin sum / sumsq -> per-thread float, wave reduce, double atomics
// ---------------------------------------------------------------------------
__launch_bounds__(256)
__global__ void margin_main(const float* __restrict__ scores,
                            const float* __restrict__ pos0,
                            const float* __restrict__ pos1,
                            float* __restrict__ rowG,
                            float* __restrict__ colG,
                            double* __restrict__ dsum) {
  const int b   = blockIdx.z;
  const int j0  = blockIdx.x * 256;
  const int i0  = blockIdx.y * 128;
  const int tid = threadIdx.x;
  const int lane = tid & 63;
  const int w    = tid >> 6;

  __shared__ float  lp0[128];
  __shared__ float  ldsCol[4][256];
  __shared__ double redS[4];
  __shared__ double redQ[4];

  if (tid < 128) {
    int i = i0 + tid;
    lp0[tid] = (i < N_) ? pos0[b * N_ + i] : 0.0f;
  }

  int   jj[4];
  bool  jload[4], jcol[4];
  float p1[4];
  float colAcc[4];
#pragma unroll
  for (int q = 0; q < 4; ++q) {
    jj[q]    = j0 + lane + 64 * q;
    jload[q] = (jj[q] < S_);   // valid score column (row pass + load)
    jcol[q]  = (jj[q] < M_);   // participates in column pass
    p1[q]    = jcol[q] ? pos1[b * M_ + jj[q]] : 0.0f;
    colAcc[q] = 0.0f;
  }
  float msum = 0.0f, msumsq = 0.0f;

  __syncthreads();

  const float* base = scores + (long long)b * PLANE;

  // number of valid k for this wave: i = i0 + w + 4k < S_
  int kmax = (S_ - i0 - w + 3) >> 2;
  if (kmax < 0) kmax = 0;
  if (kmax > 32) kmax = 32;

#pragma unroll 4
  for (int k = 0; k < kmax; ++k) {
    const int i = i0 + w + 4 * k;
    const float* __restrict__ row = base + (long long)i * S_;
    const float p0 = lp0[w + 4 * k];
    const bool rowActive = (i < N_);
    float rsum = 0.0f;
#pragma unroll
    for (int q = 0; q < 4; ++q) {
      float s = jload[q] ? row[jj[q]] : 0.0f;
      if (rowActive && jload[q]) {
        float m1 = s - p0;
        msum   += m1;
        msumsq  = fmaf(m1, m1, msumsq);
        rsum   += fmaxf(m1 + GAMMA, 0.0f);
      }
      if (jcol[q]) {
        float m2 = s - p1[q];
        msum   += m2;
        msumsq  = fmaf(m2, m2, msumsq);
        colAcc[q] += fmaxf(m2 + GAMMA, 0.0f);
      }
    }
    if (rowActive) {
#pragma unroll
      for (int off = 32; off >= 1; off >>= 1)
        rsum += __shfl_xor(rsum, off, 64);
      if (lane == 0) atomicAdd(&rowG[b * N_ + i], rsum);
    }
  }

  // stash per-wave column partials
#pragma unroll
  for (int q = 0; q < 4; ++q) ldsCol[w][q * 64 + lane] = colAcc[q];

  // wave reduce margin sums
#pragma unroll
  for (int off = 32; off >= 1; off >>= 1) {
    msum   += __shfl_xor(msum, off, 64);
    msumsq += __shfl_xor(msumsq, off, 64);
  }
  if (lane == 0) { redS[w] = (double)msum; redQ[w] = (double)msumsq; }

  __syncthreads();

  // cross-wave column reduce: thread t owns column j0 + t of the tile
  float csum = ldsCol[0][tid] + ldsCol[1][tid] + ldsCol[2][tid] + ldsCol[3][tid];
  int jc = j0 + tid;
  if (jc < M_) atomicAdd(&colG[b * M_ + jc], csum);

  if (tid == 0) {
    atomicAdd(&dsum[0], redS[0] + redS[1] + redS[2] + redS[3]);
    atomicAdd(&dsum[1], redQ[0] + redQ[1] + redQ[2] + redQ[3]);
  }
}

// ---------------------------------------------------------------------------
// Kernel 3: finalize. One block per batch element.
//   loss = (mean_i log(rowG - g + 1) + mean_j log(colG - g + 1))/2 + log(var+1)
//   rowG/colG include the gt term (== GAMMA), so add (1 - GAMMA).
// ---------------------------------------------------------------------------
__global__ void finalize_kernel(const float* __restrict__ rowG,
                                const float* __restrict__ colG,
                                const double* __restrict__ dsum,
                                float* __restrict__ out) {
  const int b = blockIdx.x;
  const int tid = threadIdx.x;
  const int lane = tid & 63;
  const int w = tid >> 6;
  float a = 0.0f;
  for (int i = tid; i < N_; i += 256) a += logf(rowG[b * N_ + i] + (1.0f - GAMMA));
  for (int j = tid; j < M_; j += 256) a += logf(colG[b * M_ + j] + (1.0f - GAMMA));
#pragma unroll
  for (int off = 32; off >= 1; off >>= 1) a += __shfl_xor(a, off, 64);
  __shared__ float red[4];
  if (lane == 0) red[w] = a;
  __syncthreads();
  if (tid == 0) {
    float total = red[0] + red[1] + red[2] + red[3];
    double sum = dsum[0], sq = dsum[1];
    double cnt = 2.0 * (double)B_ * (double)N_ * (double)M_;   // 134217728
    double var = (sq - sum * sum / cnt) / (cnt - 1.0);
    out[b] = (float)((double)total / 4096.0 + log(var + 1.0));
  }
}

// ---------------------------------------------------------------------------
extern "C" void kernel_launch(void* const* d_in, const int* in_sizes, int n_in,
                              void* d_out, int out_size, void* d_ws, size_t ws_size,
                              hipStream_t stream) {
  const float* scores = (const float*)d_in[0];
  const int*   gt0    = (const int*)d_in[1];
  const int*   gt1    = (const int*)d_in[2];
  float*       out    = (float*)d_out;

  // ws layout: [0,16) double marginSum,marginSumSq | pos0 | pos1 | rowG | colG
  double* dsum = (double*)d_ws;
  float*  pos0 = (float*)((char*)d_ws + 16);
  float*  pos1 = pos0 + B_ * N_;
  float*  rowG = pos1 + B_ * N_;
  float*  colG = rowG + B_ * N_;

  size_t zero_bytes = 16 + (size_t)4 * B_ * N_ * sizeof(float);
  hipMemsetAsync(d_ws, 0, zero_bytes, stream);

  int gth = 2 * B_ * N_;
  gather_pos<<<(gth + 255) / 256, 256, 0, stream>>>(scores, gt0, gt1, pos0, pos1);

  dim3 grid((S_ + 255) / 256, (S_ + 127) / 128, B_);
  margin_main<<<grid, 256, 0, stream>>>(scores, pos0, pos1, rowG, colG, dsum);

  finalize_kernel<<<B_, 256, 0, stream>>>(rowG, colG, dsum, out);
}

// Round 2
// 103.832 us; speedup vs baseline: 1.8125x; 1.8125x over previous
//
#include <hip/hip_runtime.h>
#include <math.h>

#define GAMMA 0.5f

constexpr int B_ = 16;
constexpr int N_ = 2048;
constexpr int M_ = 2048;
constexpr int S_ = 2049;                      // N+1 == M+1
constexpr long long PLANE = (long long)S_ * S_;

constexpr int Q_     = 8;     // columns per lane per tile
constexpr int TILE_W = 512;   // 64 * Q_
constexpr int NTILE  = 4;     // 4 * 512 = 2048 (col 2048 handled specially)
constexpr int RPW    = 16;    // rows per wave
constexpr int RPB    = 64;    // rows per block (4 waves)

// ---------------------------------------------------------------------------
// Kernel 1: gather pos0[b,i] = scores[b,i,gt0] and pos1[b,j] = scores[b,gt1,j]
// ---------------------------------------------------------------------------
__global__ void gather_pos(const float* __restrict__ scores,
                           const int* __restrict__ gt0,
                           const int* __restrict__ gt1,
                           float* __restrict__ pos0,
                           float* __restrict__ pos1) {
  int idx = blockIdx.x * blockDim.x + threadIdx.x;
  const int total = B_ * N_;
  if (idx < total) {
    int b = idx >> 11;
    int i = idx & (N_ - 1);
    int g = gt0[idx];
    if (g == -1) g = M_;
    pos0[idx] = scores[(long long)b * PLANE + (long long)i * S_ + g];
  } else if (idx < 2 * total) {
    int k = idx - total;
    int b = k >> 11;
    int j = k & (M_ - 1);
    int g = gt1[k];
    if (g == -1) g = N_;
    pos1[k] = scores[(long long)b * PLANE + (long long)g * S_ + j];
  }
}

// ---------------------------------------------------------------------------
// Kernel 2: main sweep. Grid (4 col-tiles, 33 row-stripes, 16 batch).
//   Wave w owns rows i0 + w*16 .. +15 across its 512-col tile.
//   Per row: 8 dword loads, 10 VALU/elem, ONE 3-chain shuffle reduce, store.
//   Column partials (clamp, sum, sumsq) in registers; atomicAdd at block end.
// ---------------------------------------------------------------------------
__launch_bounds__(256)
__global__ void margin_main(const float* __restrict__ scores,
                            const float* __restrict__ pos0,
                            const float* __restrict__ pos1,
                            float* __restrict__ rowC,
                            float* __restrict__ rowS,
                            float* __restrict__ rowQ,
                            float* __restrict__ colC,
                            float* __restrict__ colS,
                            float* __restrict__ colQ) {
  const int tile = blockIdx.x;            // 0..3
  const int i0   = blockIdx.y * RPB;      // 0,64,...,2048
  const int b    = blockIdx.z;
  const int tid  = threadIdx.x;
  const int lane = tid & 63;
  const int w    = tid >> 6;
  const int j0   = tile * TILE_W;

  __shared__ float lc0[RPB];              // gamma - pos0 for the row stripe
  if (tid < RPB) {
    int i = i0 + tid;
    lc0[tid] = GAMMA - ((i < N_) ? pos0[b * N_ + i] : 0.0f);
  }

  float c1[Q_], cC[Q_], cS[Q_], cQ[Q_];
#pragma unroll
  for (int q = 0; q < Q_; ++q) {
    c1[q] = GAMMA - pos1[b * M_ + j0 + 64 * q + lane];
    cC[q] = 0.0f; cS[q] = 0.0f; cQ[q] = 0.0f;
  }
  __syncthreads();

  const int ib = i0 + w * RPW;
  int rmax = S_ - ib;
  if (rmax < 0) rmax = 0;
  if (rmax > RPW) rmax = RPW;
  const float* rowp = scores + (long long)b * PLANE + (long long)ib * S_ + j0 + lane;
  const bool last_tile = (tile == NTILE - 1);

#pragma unroll 2
  for (int r = 0; r < rmax; ++r) {
    const int i = ib + r;
    const float c0 = lc0[w * RPW + r];

    float s[Q_];
#pragma unroll
    for (int q = 0; q < Q_; ++q) s[q] = rowp[q * 64];
    float extra = 0.0f;
    if (last_tile && lane == 0) extra = rowp[TILE_W];   // column 2048 (j0=1536 -> +512)

    float rC = 0.0f, rS = 0.0f, rQ = 0.0f;
#pragma unroll
    for (int q = 0; q < Q_; ++q) {
      const float sv = s[q];
      rC += fmaxf(sv + c0, 0.0f);
      rS += sv;
      rQ  = fmaf(sv, sv, rQ);
      cC[q] += fmaxf(sv + c1[q], 0.0f);
      cS[q] += sv;
      cQ[q]  = fmaf(sv, sv, cQ[q]);
    }
    if (last_tile && lane == 0) {         // col 2048: row-pass only
      rC += fmaxf(extra + c0, 0.0f);
      rS += extra;
      rQ  = fmaf(extra, extra, rQ);
    }

#pragma unroll
    for (int off = 32; off; off >>= 1) {
      rC += __shfl_xor(rC, off, 64);
      rS += __shfl_xor(rS, off, 64);
      rQ += __shfl_xor(rQ, off, 64);
    }
    if (lane == 0 && i < N_) {            // row 2048: col-pass only, skip store
      const long long o = ((long long)tile * B_ + b) * N_ + i;
      rowC[o] = rC; rowS[o] = rS; rowQ[o] = rQ;
    }
    rowp += S_;
  }

  // column partials -> global (33 row-stripes contend per address; fine)
#pragma unroll
  for (int q = 0; q < Q_; ++q) {
    const int j = j0 + 64 * q + lane;     // always < 2048
    atomicAdd(&colC[b * M_ + j], cC[q]);
    atomicAdd(&colS[b * M_ + j], cS[q]);
    atomicAdd(&colQ[b * M_ + j], cQ[q]);
  }
}

// ---------------------------------------------------------------------------
// Kernel 3: per-batch reduction of logs + moment sums (double).
// ---------------------------------------------------------------------------
__global__ void finalize1(const float* __restrict__ rowC,
                          const float* __restrict__ rowS,
                          const float* __restrict__ rowQ,
                          const float* __restrict__ colC,
                          const float* __restrict__ colS,
                          const float* __restrict__ colQ,
                          const float* __restrict__ pos0,
                          const float* __restrict__ pos1,
                          double* __restrict__ bred) {
  const int b = blockIdx.x;
  const int tid = threadIdx.x;
  const int lane = tid & 63;
  const int w = tid >> 6;
  double aL = 0.0, aM = 0.0, aQ = 0.0;

  for (int i = tid; i < N_; i += 256) {
    float rC = 0.0f, rS = 0.0f, rQ = 0.0f;
#pragma unroll
    for (int t = 0; t < NTILE; ++t) {
      const long long o = ((long long)t * B_ + b) * N_ + i;
      rC += rowC[o]; rS += rowS[o]; rQ += rowQ[o];
    }
    const double p0 = (double)pos0[b * N_ + i];
    aL += log((double)rC + 0.5);
    aM += (double)rS - 2049.0 * p0;
    aQ += (double)rQ - 2.0 * p0 * (double)rS + 2049.0 * p0 * p0;
  }
  for (int j = tid; j < M_; j += 256) {
    const float cC = colC[b * M_ + j];
    const float cS = colS[b * M_ + j];
    const float cQv = colQ[b * M_ + j];
    const double p1 = (double)pos1[b * M_ + j];
    aL += log((double)cC + 0.5);
    aM += (double)cS - 2049.0 * p1;
    aQ += (double)cQv - 2.0 * p1 * (double)cS + 2049.0 * p1 * p1;
  }

#pragma unroll
  for (int off = 32; off; off >>= 1) {
    aL += __shfl_xor(aL, off, 64);
    aM += __shfl_xor(aM, off, 64);
    aQ += __shfl_xor(aQ, off, 64);
  }
  __shared__ double red[4][3];
  if (lane == 0) { red[w][0] = aL; red[w][1] = aM; red[w][2] = aQ; }
  __syncthreads();
  if (tid == 0) {
    bred[b * 3 + 0] = red[0][0] + red[1][0] + red[2][0] + red[3][0];
    bred[b * 3 + 1] = red[0][1] + red[1][1] + red[2][1] + red[3][1];
    bred[b * 3 + 2] = red[0][2] + red[1][2] + red[2][2] + red[3][2];
  }
}

// ---------------------------------------------------------------------------
// Kernel 4: global variance + output. One block, 64 threads.
// ---------------------------------------------------------------------------
__global__ void finalize2(const double* __restrict__ bred,
                          float* __restrict__ out) {
  const int lane = threadIdx.x;
  double m = (lane < B_) ? bred[lane * 3 + 1] : 0.0;
  double q = (lane < B_) ? bred[lane * 3 + 2] : 0.0;
#pragma unroll
  for (int off = 32; off; off >>= 1) {
    m += __shfl_xor(m, off, 64);
    q += __shfl_xor(q, off, 64);
  }
  const double cnt = 2.0 * (double)B_ * (double)N_ * (double)M_;  // 134217728
  const double var = (q - m * m / cnt) / (cnt - 1.0);
  const double vl = log(var + 1.0);
  if (lane < B_) out[lane] = (float)(bred[lane * 3 + 0] / 4096.0 + vl);
}

// ---------------------------------------------------------------------------
extern "C" void kernel_launch(void* const* d_in, const int* in_sizes, int n_in,
                              void* d_out, int out_size, void* d_ws, size_t ws_size,
                              hipStream_t stream) {
  const float* scores = (const float*)d_in[0];
  const int*   gt0    = (const int*)d_in[1];
  const int*   gt1    = (const int*)d_in[2];
  float*       out    = (float*)d_out;

  // ws layout (floats unless noted):
  // colC | colS | colQ : 3 * 16*2048      (must be zeroed)
  // pos0 | pos1        : 2 * 16*2048
  // rowC | rowS | rowQ : 3 * 4*16*2048
  // bred               : 16*3 doubles
  const size_t BM = (size_t)B_ * M_;           // 32768
  float* colC = (float*)d_ws;
  float* colS = colC + BM;
  float* colQ = colS + BM;
  float* pos0 = colQ + BM;
  float* pos1 = pos0 + BM;
  float* rowC = pos1 + BM;
  float* rowS = rowC + NTILE * BM;
  float* rowQ = rowS + NTILE * BM;
  double* bred = (double*)(rowQ + NTILE * BM);

  hipMemsetAsync(colC, 0, 3 * BM * sizeof(float), stream);

  const int gth = 2 * B_ * N_;
  gather_pos<<<(gth + 255) / 256, 256, 0, stream>>>(scores, gt0, gt1, pos0, pos1);

  dim3 grid(NTILE, (S_ + RPB - 1) / RPB, B_);  // (4, 33, 16)
  margin_main<<<grid, 256, 0, stream>>>(scores, pos0, pos1,
                                        rowC, rowS, rowQ, colC, colS, colQ);

  finalize1<<<B_, 256, 0, stream>>>(rowC, rowS, rowQ, colC, colS, colQ,
                                    pos0, pos1, bred);
  finalize2<<<1, 64, 0, stream>>>(bred, out);
}

// Round 3
// 79.665 us; speedup vs baseline: 2.3624x; 1.3034x over previous
//
#include <hip/hip_runtime.h>
#include <math.h>

#define GAMMA 0.5f

constexpr int B_ = 16;
constexpr int N_ = 2048;
constexpr int M_ = 2048;
constexpr int S_ = 2049;                      // N+1 == M+1
constexpr long long PLANE = (long long)S_ * S_;

constexpr int Q_      = 8;     // columns per lane per tile
constexpr int TILE_W  = 512;   // 64 * Q_
constexpr int NTILE   = 4;     // 4 * 512 = 2048 (col 2048 via "extra")
constexpr int RPW     = 16;    // rows per wave
constexpr int RPB     = 64;    // rows per block (4 waves)
constexpr int NSTRIPE = (S_ + RPB - 1) / RPB;  // 33

// D (doubles): [0]G1 [1]G2 [2]G1r [3]G2r [4]G1c [5]G2c [6]X0 [7]X1
//              [8..23] aL per batch   [24]P0 [25]P0sq [26]P1 [27]P1sq
constexpr int NDBL = 28;

// ---------------------------------------------------------------------------
// Kernel 1: gather pos0/pos1, zero the D accumulators.
// ---------------------------------------------------------------------------
__global__ void gather_pos(const float* __restrict__ scores,
                           const int* __restrict__ gt0,
                           const int* __restrict__ gt1,
                           float* __restrict__ pos0,
                           float* __restrict__ pos1,
                           double* __restrict__ D) {
  int idx = blockIdx.x * blockDim.x + threadIdx.x;
  if (idx < NDBL) D[idx] = 0.0;
  const int total = B_ * N_;
  if (idx < total) {
    int b = idx >> 11;
    int i = idx & (N_ - 1);
    int g = gt0[idx];
    if (g == -1) g = M_;
    pos0[idx] = scores[(long long)b * PLANE + (long long)i * S_ + g];
  } else if (idx < 2 * total) {
    int k = idx - total;
    int b = k >> 11;
    int j = k & (M_ - 1);
    int g = gt1[k];
    if (g == -1) g = N_;
    pos1[k] = scores[(long long)b * PLANE + (long long)g * S_ + j];
  }
}

// ---------------------------------------------------------------------------
// Kernel 2: main sweep. Grid (4 tiles, 33 stripes, 16 b). Every plane element
// loaded exactly once. Per element: clamp into rC (row) + cC (col), plus
// global moments gs,gq and cross terms x0 += p0*s, x1 += p1*s. No atomics
// except 8 block-level f64 adds.
// ---------------------------------------------------------------------------
__launch_bounds__(256)
__global__ void margin_main(const float* __restrict__ scores,
                            const float* __restrict__ pos0,
                            const float* __restrict__ pos1,
                            float* __restrict__ rowPart,   // [NTILE][B][N]
                            float* __restrict__ colPart,   // [NSTRIPE][B][M]
                            double* __restrict__ D) {
  const int tile = blockIdx.x;
  const int st   = blockIdx.y;
  const int b    = blockIdx.z;
  const int i0   = st * RPB;
  const int tid  = threadIdx.x;
  const int lane = tid & 63;
  const int w    = tid >> 6;
  const int j0   = tile * TILE_W;

  __shared__ float lp0[RPB];
  __shared__ float ldsC[4][TILE_W];   // 8 KB
  __shared__ float ldsM[4][8];

  if (tid < RPB) {
    int i = i0 + tid;
    lp0[tid] = (i < N_) ? pos0[b * N_ + i] : 0.0f;   // p0=0 for row 2048
  }

  float p1[Q_], cC[Q_];
#pragma unroll
  for (int q = 0; q < Q_; ++q) {
    p1[q] = pos1[b * M_ + j0 + 64 * q + lane];
    cC[q] = 0.0f;
  }
  float gs = 0.f, gq = 0.f, gsr = 0.f, gqr = 0.f,
        gsc = 0.f, gqc = 0.f, x0 = 0.f, x1 = 0.f;

  __syncthreads();

  const int ib = i0 + w * RPW;
  int rmax = S_ - ib;
  rmax = rmax < 0 ? 0 : (rmax > RPW ? RPW : rmax);
  const float* rowp = scores + (long long)b * PLANE + (long long)ib * S_ + j0 + lane;
  const bool last_tile = (tile == NTILE - 1);

#pragma unroll 2
  for (int r = 0; r < rmax; ++r) {
    const int i = ib + r;
    const float p0 = lp0[w * RPW + r];
    const bool lastrow = (i == N_);

    float s[Q_];
#pragma unroll
    for (int q = 0; q < Q_; ++q) s[q] = rowp[q * 64];
    float extra = 0.0f;
    if (last_tile && lane == 0) extra = rowp[TILE_W];   // column 2048

    float rC = 0.0f;
#pragma unroll
    for (int q = 0; q < Q_; ++q) {
      const float sv = s[q];
      const float sg = sv + GAMMA;
      rC += fmaxf(sg - p0, 0.0f);          // row clamp (p0=0 on lastrow; unstored)
      x0  = fmaf(p0, sv, x0);              // row cross (0 on lastrow)
      cC[q] += fmaxf(sg - p1[q], 0.0f);    // col clamp (row 2048 included)
      x1  = fmaf(p1[q], sv, x1);           // col cross
      gs += sv;
      gq  = fmaf(sv, sv, gq);
      if (lastrow) { gsr += sv; gqr = fmaf(sv, sv, gqr); }
    }
    if (last_tile && lane == 0) {          // col 2048: row pass + G1c/G2c only
      rC  += fmaxf(extra + GAMMA - p0, 0.0f);
      x0   = fmaf(p0, extra, x0);
      gs  += extra; gq  = fmaf(extra, extra, gq);
      gsc += extra; gqc = fmaf(extra, extra, gqc);
      if (lastrow) { gsr += extra; gqr = fmaf(extra, extra, gqr); }
    }

#pragma unroll
    for (int off = 32; off; off >>= 1) rC += __shfl_xor(rC, off, 64);
    if (lane == 0 && !lastrow)
      rowPart[((long long)tile * B_ + b) * N_ + i] = rC;
    rowp += S_;
  }

  // wave-reduce the 8 moment scalars
  float m0 = gs, m1 = gq, m2 = gsr, m3 = gqr, m4 = gsc, m5 = gqc, m6 = x0, m7 = x1;
#pragma unroll
  for (int off = 32; off; off >>= 1) {
    m0 += __shfl_xor(m0, off, 64); m1 += __shfl_xor(m1, off, 64);
    m2 += __shfl_xor(m2, off, 64); m3 += __shfl_xor(m3, off, 64);
    m4 += __shfl_xor(m4, off, 64); m5 += __shfl_xor(m5, off, 64);
    m6 += __shfl_xor(m6, off, 64); m7 += __shfl_xor(m7, off, 64);
  }
  if (lane == 0) {
    ldsM[w][0] = m0; ldsM[w][1] = m1; ldsM[w][2] = m2; ldsM[w][3] = m3;
    ldsM[w][4] = m4; ldsM[w][5] = m5; ldsM[w][6] = m6; ldsM[w][7] = m7;
  }
#pragma unroll
  for (int q = 0; q < Q_; ++q) ldsC[w][q * 64 + lane] = cC[q];

  __syncthreads();

  // cross-wave column reduce, plain coalesced stores (no atomics)
  {
    const float c0v = ldsC[0][tid] + ldsC[1][tid] + ldsC[2][tid] + ldsC[3][tid];
    const float c1v = ldsC[0][tid + 256] + ldsC[1][tid + 256] +
                      ldsC[2][tid + 256] + ldsC[3][tid + 256];
    const long long base = ((long long)st * B_ + b) * M_ + j0;
    colPart[base + tid] = c0v;
    colPart[base + tid + 256] = c1v;
  }
  if (tid < 8) {
    double v = (double)ldsM[0][tid] + (double)ldsM[1][tid] +
               (double)ldsM[2][tid] + (double)ldsM[3][tid];
    atomicAdd(&D[tid], v);
  }
}

// ---------------------------------------------------------------------------
// Kernel 3: logs + pos moments. Grid (8 slices, 16 b, 2 phases), 256 thr.
// ---------------------------------------------------------------------------
__global__ void finalize1(const float* __restrict__ rowPart,
                          const float* __restrict__ colPart,
                          const float* __restrict__ pos0,
                          const float* __restrict__ pos1,
                          double* __restrict__ D) {
  const int slice = blockIdx.x;
  const int b     = blockIdx.y;
  const int phase = blockIdx.z;    // 0 = rows, 1 = cols
  const int tid   = threadIdx.x;
  const int lane  = tid & 63;
  const int w     = tid >> 6;
  const int idx   = slice * 256 + tid;

  double aL, aP, aPq;
  if (phase == 0) {
    float r = 0.f;
#pragma unroll
    for (int t = 0; t < NTILE; ++t)
      r += rowPart[((long long)t * B_ + b) * N_ + idx];
    float p = pos0[b * N_ + idx];
    aL = log((double)r + 0.5);       // log(rowC - gamma + 1)
    aP = (double)p; aPq = (double)p * p;
  } else {
    float c = 0.f;
    for (int st = 0; st < NSTRIPE; ++st)
      c += colPart[((long long)st * B_ + b) * M_ + idx];
    float p = pos1[b * M_ + idx];
    aL = log((double)c + 0.5);
    aP = (double)p; aPq = (double)p * p;
  }

#pragma unroll
  for (int off = 32; off; off >>= 1) {
    aL  += __shfl_xor(aL, off, 64);
    aP  += __shfl_xor(aP, off, 64);
    aPq += __shfl_xor(aPq, off, 64);
  }
  __shared__ double red[4][3];
  if (lane == 0) { red[w][0] = aL; red[w][1] = aP; red[w][2] = aPq; }
  __syncthreads();
  if (tid == 0) {
    atomicAdd(&D[8 + b], red[0][0] + red[1][0] + red[2][0] + red[3][0]);
    atomicAdd(&D[24 + 2 * phase], red[0][1] + red[1][1] + red[2][1] + red[3][1]);
    atomicAdd(&D[25 + 2 * phase], red[0][2] + red[1][2] + red[2][2] + red[3][2]);
  }
}

// ---------------------------------------------------------------------------
// Kernel 4: closed-form variance + output. One block, 64 threads.
// ---------------------------------------------------------------------------
__global__ void finalize2(const double* __restrict__ D,
                          float* __restrict__ out) {
  const int lane = threadIdx.x;
  const double G1 = D[0], G2 = D[1], G1r = D[2], G2r = D[3];
  const double G1c = D[4], G2c = D[5], X0 = D[6], X1 = D[7];
  const double P0 = D[24], P0q = D[25], P1 = D[26], P1q = D[27];
  const double SM = 2.0 * G1 - G1r - G1c - 2049.0 * (P0 + P1);
  const double SQ = 2.0 * G2 - G2r - G2c - 2.0 * (X0 + X1)
                    + 2049.0 * (P0q + P1q);
  const double cnt = 134217728.0;   // 2*B*N*M
  const double var = (SQ - SM * SM / cnt) / (cnt - 1.0);
  const double vl  = log(var + 1.0);
  if (lane < B_) out[lane] = (float)(D[8 + lane] / 4096.0 + vl);
}

// ---------------------------------------------------------------------------
extern "C" void kernel_launch(void* const* d_in, const int* in_sizes, int n_in,
                              void* d_out, int out_size, void* d_ws, size_t ws_size,
                              hipStream_t stream) {
  const float* scores = (const float*)d_in[0];
  const int*   gt0    = (const int*)d_in[1];
  const int*   gt1    = (const int*)d_in[2];
  float*       out    = (float*)d_out;

  double* D    = (double*)d_ws;                       // 28 doubles (256B pad)
  float* pos0  = (float*)((char*)d_ws + 256);
  float* pos1  = pos0 + (size_t)B_ * N_;
  float* rowPart = pos1 + (size_t)B_ * M_;            // NTILE*B*N floats
  float* colPart = rowPart + (size_t)NTILE * B_ * N_; // NSTRIPE*B*M floats

  const int gth = 2 * B_ * N_;
  gather_pos<<<(gth + 255) / 256, 256, 0, stream>>>(scores, gt0, gt1,
                                                    pos0, pos1, D);

  dim3 grid(NTILE, NSTRIPE, B_);    // (4, 33, 16)
  margin_main<<<grid, 256, 0, stream>>>(scores, pos0, pos1,
                                        rowPart, colPart, D);

  dim3 fgrid(8, B_, 2);
  finalize1<<<fgrid, 256, 0, stream>>>(rowPart, colPart, pos0, pos1, D);
  finalize2<<<1, 64, 0, stream>>>(D, out);
}